// Round 2
// baseline (2540.805 us; speedup 1.0000x reference)
//
#include <hip/hip_runtime.h>
#include <hip/hip_bf16.h>

typedef __hip_bfloat16 bf16;
typedef __attribute__((ext_vector_type(4))) float  floatx4;
typedef __attribute__((ext_vector_type(8))) short  short8;
typedef __attribute__((ext_vector_type(8))) __bf16 bf16x8;

constexpr int Bc = 4, Lc = 1024, Sc = 1024, DIMc = 1024, NHc = 16, DHc = 64;

// ---- MFMA dispatcher: works whether the builtin takes short8 or bf16x8 ----
template <typename V>
__device__ auto mfma_bf16_sel(V a, V b, floatx4 c, int)
    -> decltype(__builtin_amdgcn_mfma_f32_16x16x32_bf16(a, b, c, 0, 0, 0)) {
  return __builtin_amdgcn_mfma_f32_16x16x32_bf16(a, b, c, 0, 0, 0);
}
template <typename V>
__device__ floatx4 mfma_bf16_sel(V a, V b, floatx4 c, long) {
  bf16x8 a2 = __builtin_bit_cast(bf16x8, a);
  bf16x8 b2 = __builtin_bit_cast(bf16x8, b);
  return __builtin_amdgcn_mfma_f32_16x16x32_bf16(a2, b2, c, 0, 0, 0);
}
__device__ inline floatx4 mfma_bf16(short8 a, short8 b, floatx4 c) {
  return mfma_bf16_sel(a, b, c, 0);
}

union U8 { uint4 u; bf16 h[8]; };

// load 8 contiguous elements as bf16 (converting if fp32 source)
__device__ inline U8 load8(const float* p) {
    float4 f0 = ((const float4*)p)[0];
    float4 f1 = ((const float4*)p)[1];
    U8 t;
    t.h[0] = __float2bfloat16(f0.x); t.h[1] = __float2bfloat16(f0.y);
    t.h[2] = __float2bfloat16(f0.z); t.h[3] = __float2bfloat16(f0.w);
    t.h[4] = __float2bfloat16(f1.x); t.h[5] = __float2bfloat16(f1.y);
    t.h[6] = __float2bfloat16(f1.z); t.h[7] = __float2bfloat16(f1.w);
    return t;
}
__device__ inline U8 load8(const bf16* p) {
    U8 t; t.u = *(const uint4*)p; return t;
}
__device__ inline void store_elem(float* p, float v) { *p = v; }
__device__ inline void store_elem(bf16*  p, float v) { *p = __float2bfloat16(v); }

// ---------------------------------------------------------------------------
// GEMM: C[M,N] = A[M,K] @ W[K,N] + bias.  W,bias fp32; MFMA in bf16,
// fp32 accumulate.  TA in {float,bf16}, TO in {float,bf16}.
// mode 0: out[row*N + col]   (natural row-major)
// mode 1: out[((b*NH+h)*L + l)*DH + d]  head-major, row=(b,l), col=(h,d)
// Tile 64x64, BK=32, 256 threads (4 waves), each wave does a 16x64 strip.
// ---------------------------------------------------------------------------
template <typename TA, typename TO>
__global__ __launch_bounds__(256)
void gemm_bias_kernel(const TA* __restrict__ A, const float* __restrict__ W,
                      const float* __restrict__ bias, TO* __restrict__ out,
                      int M, int N, int K, int mode)
{
    __shared__ bf16 As[64][32];   // A tile, row-major (bf16)
    __shared__ bf16 Bt[64][32];   // W tile transposed: Bt[n][k] = W[k][n]

    const int tid  = threadIdx.x;
    const int wave = tid >> 6;
    const int lane = tid & 63;
    const int m0 = blockIdx.x * 64;
    const int n0 = blockIdx.y * 64;

    floatx4 acc[4];
    #pragma unroll
    for (int t = 0; t < 4; ++t) acc[t] = (floatx4){0.f, 0.f, 0.f, 0.f};

    const int ar = tid >> 2;            // 0..63
    const int ac = (tid & 3) << 3;      // 0,8,16,24
    const int wk = tid >> 3;            // 0..31
    const int wn = (tid & 7) << 3;      // 0..56

    const int mrow = (wave << 4) + (lane & 15);
    const int kk   = (lane >> 4) << 3;  // 0,8,16,24

    for (int k0 = 0; k0 < K; k0 += 32) {
        // stage A tile: 64x32, 8 elems (one 16B LDS write) per thread
        U8 at = load8(A + (size_t)(m0 + ar) * K + k0 + ac);
        *(uint4*)(&As[ar][ac]) = at.u;
        // stage W tile transposed (fp32 -> bf16)
        U8 wt = load8(W + (size_t)(k0 + wk) * N + n0 + wn);
        #pragma unroll
        for (int j = 0; j < 8; ++j) Bt[wn + j][wk] = wt.h[j];
        __syncthreads();

        short8 a8 = *(const short8*)(&As[mrow][kk]);
        #pragma unroll
        for (int t = 0; t < 4; ++t) {
            short8 b8 = *(const short8*)(&Bt[(t << 4) + (lane & 15)][kk]);
            acc[t] = mfma_bf16(a8, b8, acc[t]);
        }
        __syncthreads();
    }

    // epilogue: C/D layout col = lane&15, row = (lane>>4)*4 + r  [m89/m91]
    #pragma unroll
    for (int t = 0; t < 4; ++t) {
        const int col = n0 + (t << 4) + (lane & 15);
        const float bval = bias[col];
        #pragma unroll
        for (int r = 0; r < 4; ++r) {
            const int row = m0 + (wave << 4) + ((lane >> 4) << 2) + r;
            const float v = acc[t][r] + bval;
            size_t idx;
            if (mode == 0) {
                idx = (size_t)row * N + col;
            } else {
                const int bb = row >> 10, ll = row & (Lc - 1);
                const int hh = col >> 6,  dd = col & 63;
                idx = (((size_t)(bb * NHc + hh) * Lc + ll) * DHc) + dd;
            }
            store_elem(out + idx, v);
        }
    }
}

// ---------------------------------------------------------------------------
// Attention: one block per (b,h,l).  K/V (bf16 in ws) staged in 128-row LDS
// chunks (fp32, +1 pad -> conflict-free).  Masked/biased softmax with causal
// + row-any fix; mask int32, pos_bias fp32.
// Writes O in natural (b,l,h*64+d) bf16 layout for the output projection.
// ---------------------------------------------------------------------------
__global__ __launch_bounds__(256)
void attn_kernel(const bf16* __restrict__ qh, const bf16* __restrict__ kh,
                 const bf16* __restrict__ vh, const int* __restrict__ mask,
                 const float* __restrict__ pos_bias,
                 const int* __restrict__ is_causal_p, bf16* __restrict__ o)
{
    __shared__ float kv[128][DHc + 1];   // 33 KB, K then V chunks
    __shared__ float p_s[Sc];            // 4 KB scores/probs
    __shared__ float pp[2][128];
    __shared__ float q_s[DHc];
    __shared__ float opart[4][DHc];
    __shared__ float red[4];
    __shared__ int flag;

    const int tid  = threadIdx.x;
    const int lane = tid & 63;
    const int wave = tid >> 6;
    const int blk = blockIdx.x;
    const int l  = blk & (Lc - 1);
    const int bh = blk >> 10;            // b*NH + h
    const int h  = bh & (NHc - 1);
    const int b  = bh >> 4;

    const bool causal = (is_causal_p[0] != 0);
    const int  limit  = causal ? (l + (Sc - Lc)) : (Sc - 1);  // allowed s <= limit

    if (tid < DHc)
        q_s[tid] = __bfloat162float(qh[((size_t)bh * Lc + l) * DHc + tid]);
    if (tid == 0) flag = 0;
    __syncthreads();

    // row_any over (attn_mask & causal)
    const int* mrow = mask + ((size_t)b * Lc + l) * Sc;
    int any = 0;
    for (int s = tid; s < Sc; s += 256)
        if (s <= limit && mrow[s] != 0) any = 1;
    if (any) atomicOr(&flag, 1);
    __syncthreads();
    const bool allow_all = (flag == 0);   // no allowed key -> attend everywhere

    const bf16* Kb = kh + (size_t)bh * Sc * DHc;
    const float* bias_row = pos_bias + ((size_t)bh * Lc + l) * Sc;
    const float scale = 0.125f;           // 1/sqrt(64)

    // ---- scores ----
    for (int c = 0; c < Sc; c += 128) {
        const bf16* src = Kb + (size_t)c * DHc;
        #pragma unroll
        for (int it = 0; it < 4; ++it) {
            const int e = (tid << 3) + (it << 11);
            const int sr = e >> 6, d = e & 63;
            union { uint4 u; unsigned short us[8]; } r;
            r.u = *(const uint4*)(src + e);
            #pragma unroll
            for (int j = 0; j < 8; ++j)
                kv[sr][d + j] = __uint_as_float(((unsigned)r.us[j]) << 16);
        }
        __syncthreads();
        {
            const int sl = tid & 127, dh2 = tid >> 7;
            float part = 0.f;
            #pragma unroll
            for (int d = 0; d < 32; ++d)
                part += q_s[(dh2 << 5) + d] * kv[sl][(dh2 << 5) + d];
            pp[dh2][sl] = part;
        }
        __syncthreads();
        if (tid < 128) {
            const int s = c + tid;
            const float dot = (pp[0][tid] + pp[1][tid]) * scale;
            const bool ok = allow_all || (s <= limit && mrow[s] != 0);
            p_s[s] = ok ? dot + bias_row[s] : -3.0e38f;
        }
        __syncthreads();
    }

    // ---- softmax ----
    float mx = -3.4e38f;
    for (int s = tid; s < Sc; s += 256) mx = fmaxf(mx, p_s[s]);
    #pragma unroll
    for (int off = 32; off > 0; off >>= 1) mx = fmaxf(mx, __shfl_down(mx, off));
    if (lane == 0) red[wave] = mx;
    __syncthreads();
    const float gmax = fmaxf(fmaxf(red[0], red[1]), fmaxf(red[2], red[3]));
    __syncthreads();

    float lsum = 0.f;
    for (int s = tid; s < Sc; s += 256) {
        const float e = __expf(p_s[s] - gmax);
        p_s[s] = e;
        lsum += e;
    }
    #pragma unroll
    for (int off = 32; off > 0; off >>= 1) lsum += __shfl_down(lsum, off);
    if (lane == 0) red[wave] = lsum;
    __syncthreads();
    const float gsum = red[0] + red[1] + red[2] + red[3];

    // ---- O = P @ V ----
    const bf16* Vb = vh + (size_t)bh * Sc * DHc;
    const int d = tid & 63, g = tid >> 6;
    float oacc = 0.f;
    for (int c = 0; c < Sc; c += 128) {
        const bf16* src = Vb + (size_t)c * DHc;
        #pragma unroll
        for (int it = 0; it < 4; ++it) {
            const int e = (tid << 3) + (it << 11);
            const int sr = e >> 6, dd = e & 63;
            union { uint4 u; unsigned short us[8]; } r;
            r.u = *(const uint4*)(src + e);
            #pragma unroll
            for (int j = 0; j < 8; ++j)
                kv[sr][dd + j] = __uint_as_float(((unsigned)r.us[j]) << 16);
        }
        __syncthreads();
        #pragma unroll 8
        for (int s = g; s < 128; s += 4)
            oacc += p_s[c + s] * kv[s][d];
        __syncthreads();
    }
    opart[g][d] = oacc;
    __syncthreads();
    if (tid < DHc) {
        const float val =
            (opart[0][tid] + opart[1][tid] + opart[2][tid] + opart[3][tid]) / gsum;
        o[((size_t)(b * Lc + l) * DIMc) + h * DHc + tid] = __float2bfloat16(val);
    }
}

// ---------------------------------------------------------------------------
extern "C" void kernel_launch(void* const* d_in, const int* in_sizes, int n_in,
                              void* d_out, int out_size, void* d_ws, size_t ws_size,
                              hipStream_t stream)
{
    (void)in_sizes; (void)n_in; (void)out_size; (void)ws_size;

    // dtypes per reference: all float tensors are float32 on device;
    // attn_mask (bool) and is_causal (python int) are int32.
    const float* q        = (const float*)d_in[0];
    const float* k        = (const float*)d_in[1];
    const float* v        = (const float*)d_in[2];
    const int*   mask     = (const int*)d_in[3];
    const float* pos_bias = (const float*)d_in[4];
    const float* Wq = (const float*)d_in[5];
    const float* bq = (const float*)d_in[6];
    const float* Wk = (const float*)d_in[7];
    const float* bk = (const float*)d_in[8];
    const float* Wv = (const float*)d_in[9];
    const float* bv = (const float*)d_in[10];
    const float* Wp = (const float*)d_in[11];
    const float* bp = (const float*)d_in[12];
    const int*   is_causal = (const int*)d_in[13];

    const size_t per = (size_t)Bc * NHc * Lc * DHc;  // 4M elems (bf16)
    bf16* qh = (bf16*)d_ws;
    bf16* kh = qh + per;
    bf16* vh = kh + per;
    bf16* oh = vh + per;
    float* outp = (float*)d_out;

    const int Mrows = Bc * Lc;       // 4096
    dim3 gg(Mrows / 64, DIMc / 64);  // (64, 16)
    dim3 bb(256);

    gemm_bias_kernel<float, bf16><<<gg, bb, 0, stream>>>(q, Wq, bq, qh, Mrows, DIMc, DIMc, 1);
    gemm_bias_kernel<float, bf16><<<gg, bb, 0, stream>>>(k, Wk, bk, kh, Mrows, DIMc, DIMc, 1);
    gemm_bias_kernel<float, bf16><<<gg, bb, 0, stream>>>(v, Wv, bv, vh, Mrows, DIMc, DIMc, 1);

    attn_kernel<<<Bc * NHc * Lc, bb, 0, stream>>>(qh, kh, vh, mask, pos_bias,
                                                  is_causal, oh);

    gemm_bias_kernel<bf16, float><<<gg, bb, 0, stream>>>(oh, Wp, bp, outp, Mrows, DIMc, DIMc, 0);
}

// Round 3
// 677.313 us; speedup vs baseline: 3.7513x; 3.7513x over previous
//
#include <hip/hip_runtime.h>
#include <hip/hip_bf16.h>

typedef __hip_bfloat16 bf16;
typedef __attribute__((ext_vector_type(4))) float  floatx4;
typedef __attribute__((ext_vector_type(8))) short  short8;
typedef __attribute__((ext_vector_type(8))) __bf16 bf16x8;

constexpr int Bc = 4, Lc = 1024, Sc = 1024, DIMc = 1024, NHc = 16, DHc = 64;

// ---- MFMA dispatcher: works whether the builtin takes short8 or bf16x8 ----
template <typename V>
__device__ auto mfma_bf16_sel(V a, V b, floatx4 c, int)
    -> decltype(__builtin_amdgcn_mfma_f32_16x16x32_bf16(a, b, c, 0, 0, 0)) {
  return __builtin_amdgcn_mfma_f32_16x16x32_bf16(a, b, c, 0, 0, 0);
}
template <typename V>
__device__ floatx4 mfma_bf16_sel(V a, V b, floatx4 c, long) {
  bf16x8 a2 = __builtin_bit_cast(bf16x8, a);
  bf16x8 b2 = __builtin_bit_cast(bf16x8, b);
  return __builtin_amdgcn_mfma_f32_16x16x32_bf16(a2, b2, c, 0, 0, 0);
}
__device__ inline floatx4 mfma_bf16(short8 a, short8 b, floatx4 c) {
  return mfma_bf16_sel(a, b, c, 0);
}

union U8 { uint4 u; bf16 h[8]; };

__device__ inline U8 load8(const float* p) {
    float4 f0 = ((const float4*)p)[0];
    float4 f1 = ((const float4*)p)[1];
    U8 t;
    t.h[0] = __float2bfloat16(f0.x); t.h[1] = __float2bfloat16(f0.y);
    t.h[2] = __float2bfloat16(f0.z); t.h[3] = __float2bfloat16(f0.w);
    t.h[4] = __float2bfloat16(f1.x); t.h[5] = __float2bfloat16(f1.y);
    t.h[6] = __float2bfloat16(f1.z); t.h[7] = __float2bfloat16(f1.w);
    return t;
}
__device__ inline U8 load8(const bf16* p) {
    U8 t; t.u = *(const uint4*)p; return t;
}
__device__ inline void store_elem(float* p, float v) { *p = v; }
__device__ inline void store_elem(bf16*  p, float v) { *p = __float2bfloat16(v); }

// ---------------------------------------------------------------------------
// GEMM: C[M,N] = A[M,K] @ W[K,N] + bias.  MFMA bf16, fp32 accumulate.
// mode 0: out[row*N + col]
// mode 1: out[((b*NH+h)*L + l)*DH + d]          head-major
// mode 2: out[((b*NH+h)*DH + d)*S + l]          head-major TRANSPOSED (for V)
// ---------------------------------------------------------------------------
template <typename TA, typename TO>
__global__ __launch_bounds__(256)
void gemm_bias_kernel(const TA* __restrict__ A, const float* __restrict__ W,
                      const float* __restrict__ bias, TO* __restrict__ out,
                      int M, int N, int K, int mode)
{
    __shared__ bf16 As[64][32];
    __shared__ bf16 Bt[64][32];

    const int tid  = threadIdx.x;
    const int wave = tid >> 6;
    const int lane = tid & 63;
    const int m0 = blockIdx.x * 64;
    const int n0 = blockIdx.y * 64;

    floatx4 acc[4];
    #pragma unroll
    for (int t = 0; t < 4; ++t) acc[t] = (floatx4){0.f, 0.f, 0.f, 0.f};

    const int ar = tid >> 2;
    const int ac = (tid & 3) << 3;
    const int wk = tid >> 3;
    const int wn = (tid & 7) << 3;

    const int mrow = (wave << 4) + (lane & 15);
    const int kk   = (lane >> 4) << 3;

    for (int k0 = 0; k0 < K; k0 += 32) {
        U8 at = load8(A + (size_t)(m0 + ar) * K + k0 + ac);
        *(uint4*)(&As[ar][ac]) = at.u;
        U8 wt = load8(W + (size_t)(k0 + wk) * N + n0 + wn);
        #pragma unroll
        for (int j = 0; j < 8; ++j) Bt[wn + j][wk] = wt.h[j];
        __syncthreads();

        short8 a8 = *(const short8*)(&As[mrow][kk]);
        #pragma unroll
        for (int t = 0; t < 4; ++t) {
            short8 b8 = *(const short8*)(&Bt[(t << 4) + (lane & 15)][kk]);
            acc[t] = mfma_bf16(a8, b8, acc[t]);
        }
        __syncthreads();
    }

    #pragma unroll
    for (int t = 0; t < 4; ++t) {
        const int col = n0 + (t << 4) + (lane & 15);
        const float bval = bias[col];
        #pragma unroll
        for (int r = 0; r < 4; ++r) {
            const int row = m0 + (wave << 4) + ((lane >> 4) << 2) + r;
            const float v = acc[t][r] + bval;
            const int bb = row >> 10, ll = row & (Lc - 1);
            const int hh = col >> 6,  dd = col & 63;
            size_t idx;
            if (mode == 0)      idx = (size_t)row * N + col;
            else if (mode == 1) idx = (((size_t)(bb * NHc + hh) * Lc + ll) * DHc) + dd;
            else                idx = (((size_t)(bb * NHc + hh) * DHc + dd) * Sc) + ll;
            store_elem(out + idx, v);
        }
    }
}

// ---------------------------------------------------------------------------
// Flash MFMA attention.
// Grid: (B*NH) * (L/64) blocks, 256 threads (4 waves).  Each wave owns 16
// Q-rows.  Per 64-key chunk: stage K[s][d] and Vt[d][s] in LDS (stride 72,
// bank-even), QK^T via mfma_16x16x32_bf16 (Q frags in registers), fp32
// mask/bias/online-softmax in C-layout, P->LDS->A-layout, PV MFMA.
// Causal early-exit per q-tile unless a row needs the row-any fix.
// ---------------------------------------------------------------------------
constexpr int PADk = 72;   // LDS row stride (elems); 36 dwords == 4 mod 32

__global__ __launch_bounds__(256)
void flash_attn_kernel(const bf16* __restrict__ qh, const bf16* __restrict__ kh,
                       const bf16* __restrict__ vt, const int* __restrict__ mask,
                       const float* __restrict__ pos_bias,
                       const int* __restrict__ is_causal_p, bf16* __restrict__ o)
{
    __shared__ bf16 Ks[64 * PADk];       // [s][d]
    __shared__ bf16 Vs[64 * PADk];       // [d][s]
    __shared__ bf16 Pw[4][16 * PADk];    // per-wave P tile [qrow][s]
    __shared__ int rowany[64];
    __shared__ int hasfix_s;

    const int tid  = threadIdx.x;
    const int lane = tid & 63;
    const int wave = tid >> 6;
    const int n = lane & 15;            // MFMA col index / frag row
    const int g = lane >> 4;            // MFMA row-group / k-slice

    const int qt = blockIdx.x & 15;
    const int bh = blockIdx.x >> 4;
    const int h  = bh & (NHc - 1);
    const int b  = bh >> 4;
    const int l0 = qt * 64;
    const bool causal = (is_causal_p[0] != 0);

    // ---- row-any flags (does row have >=1 allowed key under mask&causal?) --
    if (tid < 64) rowany[tid] = 0;
    if (tid == 0) hasfix_s = 0;
    __syncthreads();
    {
        const int row = tid >> 2, part = tid & 3;
        const int l = l0 + row;
        const int limit = causal ? l : (Sc - 1);
        const int* mrow = mask + ((size_t)b * Lc + l) * Sc;
        int any = 0;
        for (int s = part * 256; s < part * 256 + 256; ++s) {
            if (s <= limit && mrow[s] != 0) { any = 1; break; }
        }
        if (any) atomicOr(&rowany[row], 1);
    }
    __syncthreads();
    if (tid < 64 && rowany[tid] == 0) atomicOr(&hasfix_s, 1);
    __syncthreads();
    const bool hasfix = (hasfix_s != 0);

    // ---- Q fragments: held in registers for the whole kernel ----
    const int qrow_frag = l0 + wave * 16 + n;
    const bf16* qp = qh + ((size_t)bh * Lc + qrow_frag) * DHc;
    const short8 qf0 = *(const short8*)(qp + g * 8);
    const short8 qf1 = *(const short8*)(qp + 32 + g * 8);

    floatx4 oacc[4];
    #pragma unroll
    for (int t = 0; t < 4; ++t) oacc[t] = (floatx4){0.f, 0.f, 0.f, 0.f};
    float m_run[4], l_run[4];
    #pragma unroll
    for (int r = 0; r < 4; ++r) { m_run[r] = -3.0e38f; l_run[r] = 0.f; }

    int nchunk = Sc / 64;
    if (causal && !hasfix) nchunk = qt + 1;   // chunks past l0+63 fully masked

    for (int c = 0; c < nchunk; ++c) {
        const int s0 = c * 64;
        __syncthreads();                     // prev chunk's LDS reads done
        // ---- stage K chunk [64s x 64d] and Vt chunk [64d x 64s] ----
        #pragma unroll
        for (int it = 0; it < 2; ++it) {
            const int e  = tid * 8 + it * 2048;
            const int r0 = e >> 6, c0 = e & 63;
            *(uint4*)(Ks + r0 * PADk + c0) =
                *(const uint4*)(kh + ((size_t)bh * Sc + s0 + r0) * DHc + c0);
            *(uint4*)(Vs + r0 * PADk + c0) =
                *(const uint4*)(vt + ((size_t)bh * DHc + r0) * Sc + s0 + c0);
        }
        __syncthreads();

        // ---- prefetch mask + bias for this wave's 16x64 score tile ----
        float bi[4][4]; int mk[4][4];
        #pragma unroll
        for (int r = 0; r < 4; ++r) {
            const int l = l0 + wave * 16 + g * 4 + r;
            const size_t mb = ((size_t)b  * Lc + l) * Sc + s0 + n;
            const size_t pb = ((size_t)bh * Lc + l) * Sc + s0 + n;
            #pragma unroll
            for (int t = 0; t < 4; ++t) {
                mk[r][t] = mask[mb + 16 * t];
                bi[r][t] = pos_bias[pb + 16 * t];
            }
        }

        // ---- QK^T:  scv[t] = Q_wave(16x64) . K_chunk(16t..16t+15, :)^T ----
        floatx4 scv[4];
        #pragma unroll
        for (int t = 0; t < 4; ++t) scv[t] = (floatx4){0.f, 0.f, 0.f, 0.f};
        #pragma unroll
        for (int t = 0; t < 4; ++t) {
            short8 kb0 = *(const short8*)(Ks + (16 * t + n) * PADk + g * 8);
            short8 kb1 = *(const short8*)(Ks + (16 * t + n) * PADk + 32 + g * 8);
            scv[t] = mfma_bf16(qf0, kb0, scv[t]);
            scv[t] = mfma_bf16(qf1, kb1, scv[t]);
        }

        // ---- mask/bias + online softmax (per row r) ----
        #pragma unroll
        for (int r = 0; r < 4; ++r) {
            const int row = wave * 16 + g * 4 + r;
            const int l = l0 + row;
            const int limit = causal ? l : (Sc - 1);
            const bool fix = (rowany[row] == 0);
            float vals[4];
            #pragma unroll
            for (int t = 0; t < 4; ++t) {
                const int s = s0 + 16 * t + n;
                const bool ok = fix || (s <= limit && mk[r][t] != 0);
                vals[t] = ok ? scv[t][r] * 0.125f + bi[r][t] : -3.0e38f;
            }
            float cm = fmaxf(fmaxf(vals[0], vals[1]), fmaxf(vals[2], vals[3]));
            cm = fmaxf(cm, __shfl_xor(cm, 1));
            cm = fmaxf(cm, __shfl_xor(cm, 2));
            cm = fmaxf(cm, __shfl_xor(cm, 4));
            cm = fmaxf(cm, __shfl_xor(cm, 8));
            const float mnew = fmaxf(m_run[r], cm);
            const float alpha = __expf(m_run[r] - mnew);
            float csum = 0.f;
            #pragma unroll
            for (int t = 0; t < 4; ++t) {
                const float p = (vals[t] < -1.0e37f) ? 0.f : __expf(vals[t] - mnew);
                csum += p;
                Pw[wave][row % 16 * PADk + 16 * t + n] = __float2bfloat16(p);
            }
            csum += __shfl_xor(csum, 1);
            csum += __shfl_xor(csum, 2);
            csum += __shfl_xor(csum, 4);
            csum += __shfl_xor(csum, 8);
            l_run[r] = l_run[r] * alpha + csum;
            m_run[r] = mnew;
            #pragma unroll
            for (int t = 0; t < 4; ++t) oacc[t][r] *= alpha;
        }
        __syncthreads();   // P tiles visible (cross-lane)

        // ---- PV: oacc[t] += P(16x64) . V_chunk(:, 16t..16t+15) ----
        #pragma unroll
        for (int sc2 = 0; sc2 < 2; ++sc2) {
            short8 pa = *(const short8*)(Pw[wave] + n * PADk + sc2 * 32 + g * 8);
            #pragma unroll
            for (int t = 0; t < 4; ++t) {
                short8 vb = *(const short8*)(Vs + (16 * t + n) * PADk + sc2 * 32 + g * 8);
                oacc[t] = mfma_bf16(pa, vb, oacc[t]);
            }
        }
    }

    // ---- epilogue: O /= l_run, write natural (b,l,h*64+d) bf16 ----
    #pragma unroll
    for (int r = 0; r < 4; ++r) {
        const int l = l0 + wave * 16 + g * 4 + r;
        const float inv = 1.f / l_run[r];
        #pragma unroll
        for (int t = 0; t < 4; ++t) {
            const int d = 16 * t + n;
            o[((size_t)(b * Lc + l)) * DIMc + h * DHc + d] =
                __float2bfloat16(oacc[t][r] * inv);
        }
    }
}

// ---------------------------------------------------------------------------
extern "C" void kernel_launch(void* const* d_in, const int* in_sizes, int n_in,
                              void* d_out, int out_size, void* d_ws, size_t ws_size,
                              hipStream_t stream)
{
    (void)in_sizes; (void)n_in; (void)out_size; (void)ws_size;

    const float* q        = (const float*)d_in[0];
    const float* k        = (const float*)d_in[1];
    const float* v        = (const float*)d_in[2];
    const int*   mask     = (const int*)d_in[3];
    const float* pos_bias = (const float*)d_in[4];
    const float* Wq = (const float*)d_in[5];
    const float* bq = (const float*)d_in[6];
    const float* Wk = (const float*)d_in[7];
    const float* bk = (const float*)d_in[8];
    const float* Wv = (const float*)d_in[9];
    const float* bv = (const float*)d_in[10];
    const float* Wp = (const float*)d_in[11];
    const float* bp = (const float*)d_in[12];
    const int*   is_causal = (const int*)d_in[13];

    const size_t per = (size_t)Bc * NHc * Lc * DHc;  // 4M elems (bf16)
    bf16* qh = (bf16*)d_ws;
    bf16* kh = qh + per;
    bf16* vt = kh + per;      // V transposed per head: [bh][d][s]
    bf16* oh = vt + per;
    float* outp = (float*)d_out;

    const int Mrows = Bc * Lc;       // 4096
    dim3 gg(Mrows / 64, DIMc / 64);
    dim3 bb(256);

    gemm_bias_kernel<float, bf16><<<gg, bb, 0, stream>>>(q, Wq, bq, qh, Mrows, DIMc, DIMc, 1);
    gemm_bias_kernel<float, bf16><<<gg, bb, 0, stream>>>(k, Wk, bk, kh, Mrows, DIMc, DIMc, 1);
    gemm_bias_kernel<float, bf16><<<gg, bb, 0, stream>>>(v, Wv, bv, vt, Mrows, DIMc, DIMc, 2);

    flash_attn_kernel<<<(Bc * NHc) * (Lc / 64), bb, 0, stream>>>(
        qh, kh, vt, mask, pos_bias, is_causal, oh);

    gemm_bias_kernel<bf16, float><<<gg, bb, 0, stream>>>(oh, Wp, bp, outp, Mrows, DIMc, DIMc, 0);
}

// Round 4
// 600.493 us; speedup vs baseline: 4.2312x; 1.1279x over previous
//
#include <hip/hip_runtime.h>
#include <hip/hip_bf16.h>

typedef __hip_bfloat16 bf16;
typedef __attribute__((ext_vector_type(4))) float  floatx4;
typedef __attribute__((ext_vector_type(8))) short  short8;
typedef __attribute__((ext_vector_type(8))) __bf16 bf16x8;

constexpr int Bc = 4, Lc = 1024, Sc = 1024, DIMc = 1024, NHc = 16, DHc = 64;

// ---- MFMA dispatcher: works whether the builtin takes short8 or bf16x8 ----
template <typename V>
__device__ auto mfma_bf16_sel(V a, V b, floatx4 c, int)
    -> decltype(__builtin_amdgcn_mfma_f32_16x16x32_bf16(a, b, c, 0, 0, 0)) {
  return __builtin_amdgcn_mfma_f32_16x16x32_bf16(a, b, c, 0, 0, 0);
}
template <typename V>
__device__ floatx4 mfma_bf16_sel(V a, V b, floatx4 c, long) {
  bf16x8 a2 = __builtin_bit_cast(bf16x8, a);
  bf16x8 b2 = __builtin_bit_cast(bf16x8, b);
  return __builtin_amdgcn_mfma_f32_16x16x32_bf16(a2, b2, c, 0, 0, 0);
}
__device__ inline floatx4 mfma_bf16(short8 a, short8 b, floatx4 c) {
  return mfma_bf16_sel(a, b, c, 0);
}

union U8 { uint4 u; bf16 h[8]; };

__device__ inline U8 load8(const float* p) {
    float4 f0 = ((const float4*)p)[0];
    float4 f1 = ((const float4*)p)[1];
    U8 t;
    t.h[0] = __float2bfloat16(f0.x); t.h[1] = __float2bfloat16(f0.y);
    t.h[2] = __float2bfloat16(f0.z); t.h[3] = __float2bfloat16(f0.w);
    t.h[4] = __float2bfloat16(f1.x); t.h[5] = __float2bfloat16(f1.y);
    t.h[6] = __float2bfloat16(f1.z); t.h[7] = __float2bfloat16(f1.w);
    return t;
}
__device__ inline void store_elem(float* p, float v) { *p = v; }
__device__ inline void store_elem(bf16*  p, float v) { *p = __float2bfloat16(v); }

// ---------------------------------------------------------------------------
// Prep: blocks [0,6144): cast q,k,v fp32->bf16 (2048 elems/block).
//       blocks [6144,7168): transpose+cast the 4 weights into Wt[n][k] bf16
//       via 64x64 LDS tiles (256 blocks per weight).
// ---------------------------------------------------------------------------
__global__ __launch_bounds__(256)
void prep_kernel(const float* __restrict__ q, const float* __restrict__ k,
                 const float* __restrict__ v,
                 const float* __restrict__ Wq, const float* __restrict__ Wk,
                 const float* __restrict__ Wv, const float* __restrict__ Wp,
                 bf16* __restrict__ qb, bf16* __restrict__ kb,
                 bf16* __restrict__ vb,
                 bf16* __restrict__ wqt, bf16* __restrict__ wkt,
                 bf16* __restrict__ wvt, bf16* __restrict__ wpt)
{
    __shared__ float tile[64][68];
    const int tid = threadIdx.x;
    int blk = blockIdx.x;

    if (blk < 6144) {
        const float* src = (blk < 2048) ? q : (blk < 4096) ? k : v;
        bf16*        dst = (blk < 2048) ? qb : (blk < 4096) ? kb : vb;
        const int off = (blk & 2047) * 2048 + tid * 8;
        U8 t = load8(src + off);
        *(uint4*)(dst + off) = t.u;
    } else {
        blk -= 6144;
        const int w  = blk >> 8, t2 = blk & 255;
        const float* W  = (w == 0) ? Wq : (w == 1) ? Wk : (w == 2) ? Wv : Wp;
        bf16*        Wt = (w == 0) ? wqt : (w == 1) ? wkt : (w == 2) ? wvt : wpt;
        const int tk = (t2 >> 4) << 6;   // k-tile base
        const int tn = (t2 & 15) << 6;   // n-tile base
        #pragma unroll
        for (int i = 0; i < 4; ++i) {
            const int r = (tid >> 4) + i * 16;   // 0..63 (k within tile)
            const int c = (tid & 15) << 2;       // 0..60 (n within tile)
            *(float4*)(&tile[r][c]) =
                *(const float4*)(W + (size_t)(tk + r) * DIMc + tn + c);
        }
        __syncthreads();
        #pragma unroll
        for (int j = 0; j < 2; ++j) {
            const int nn = tid >> 2;                  // 0..63
            const int kc = (tid & 3) + j * 4;         // 0..7
            U8 o;
            #pragma unroll
            for (int u = 0; u < 8; ++u)
                o.h[u] = __float2bfloat16(tile[kc * 8 + u][nn]);
            *(uint4*)(Wt + (size_t)(tn + nn) * DIMc + tk + kc * 8) = o.u;
        }
    }
}

// ---------------------------------------------------------------------------
// GEMM (B^T form): C[m][n] = sum_k A[m][k]*Bt[n][k] + bias[n].
// A: 4096xK bf16, Bt: 1024xK bf16 (K=1024).  128x128 tile, BK=64, 4 waves
// in 2x2, each wave 64x64 = 4x4 MFMA tiles.  LDS stride 72 (bank-even).
// mode 0: out[row*N + col] fp32
// mode 1: out[((b*NH+h)*L + l)*DH + d] bf16
// mode 2: out[((b*NH+h)*DH + d)*S + l] bf16  (transposed V for attention)
// ---------------------------------------------------------------------------
constexpr int GPAD = 72;

template <typename TO>
__global__ __launch_bounds__(256)
void gemm_bt_kernel(const bf16* __restrict__ A, const bf16* __restrict__ Bt,
                    const float* __restrict__ bias, TO* __restrict__ out,
                    int mode)
{
    __shared__ bf16 As[128 * GPAD];
    __shared__ bf16 Bs[128 * GPAD];

    const int tid  = threadIdx.x;
    const int wave = tid >> 6;
    const int lane = tid & 63;
    const int n = lane & 15, g = lane >> 4;
    const int m0 = blockIdx.x * 128;
    const int n0 = blockIdx.y * 128;
    const int wq_m = (wave & 1) * 64, wq_n = (wave >> 1) * 64;

    floatx4 acc[4][4];
    #pragma unroll
    for (int a = 0; a < 4; ++a)
        #pragma unroll
        for (int b2 = 0; b2 < 4; ++b2)
            acc[a][b2] = (floatx4){0.f, 0.f, 0.f, 0.f};

    const int srow   = tid >> 3;          // 0..31
    const int schunk = (tid & 7) * 8;     // 0..56

    for (int k0 = 0; k0 < DIMc; k0 += 64) {
        #pragma unroll
        for (int i = 0; i < 4; ++i) {
            const int r = srow + i * 32;
            *(uint4*)(&As[r * GPAD + schunk]) =
                *(const uint4*)(A + (size_t)(m0 + r) * DIMc + k0 + schunk);
            *(uint4*)(&Bs[r * GPAD + schunk]) =
                *(const uint4*)(Bt + (size_t)(n0 + r) * DIMc + k0 + schunk);
        }
        __syncthreads();
        #pragma unroll
        for (int ks = 0; ks < 2; ++ks) {
            short8 af[4], bf_[4];
            #pragma unroll
            for (int t = 0; t < 4; ++t) {
                af[t]  = *(const short8*)(&As[(wq_m + t * 16 + n) * GPAD + ks * 32 + g * 8]);
                bf_[t] = *(const short8*)(&Bs[(wq_n + t * 16 + n) * GPAD + ks * 32 + g * 8]);
            }
            #pragma unroll
            for (int tm = 0; tm < 4; ++tm)
                #pragma unroll
                for (int tn = 0; tn < 4; ++tn)
                    acc[tm][tn] = mfma_bf16(af[tm], bf_[tn], acc[tm][tn]);
        }
        __syncthreads();
    }

    // epilogue: C/D layout col = lane&15 (=n), row = g*4 + r
    #pragma unroll
    for (int tn = 0; tn < 4; ++tn) {
        const int col = n0 + wq_n + tn * 16 + n;
        const float bval = bias[col];
        #pragma unroll
        for (int tm = 0; tm < 4; ++tm) {
            #pragma unroll
            for (int r = 0; r < 4; ++r) {
                const int row = m0 + wq_m + tm * 16 + g * 4 + r;
                const float vv = acc[tm][tn][r] + bval;
                const int bb = row >> 10, ll = row & (Lc - 1);
                const int hh = col >> 6,  dd = col & 63;
                size_t idx;
                if (mode == 0)      idx = (size_t)row * DIMc + col;
                else if (mode == 1) idx = (((size_t)(bb * NHc + hh) * Lc + ll) * DHc) + dd;
                else                idx = (((size_t)(bb * NHc + hh) * DHc + dd) * Sc) + ll;
                store_elem(out + idx, vv);
            }
        }
    }
}

// ---------------------------------------------------------------------------
// Flash MFMA attention (unchanged from round 3 — correct at absmax 0.0078).
// ---------------------------------------------------------------------------
constexpr int PADk = 72;

__global__ __launch_bounds__(256)
void flash_attn_kernel(const bf16* __restrict__ qh, const bf16* __restrict__ kh,
                       const bf16* __restrict__ vt, const int* __restrict__ mask,
                       const float* __restrict__ pos_bias,
                       const int* __restrict__ is_causal_p, bf16* __restrict__ o)
{
    __shared__ bf16 Ks[64 * PADk];
    __shared__ bf16 Vs[64 * PADk];
    __shared__ bf16 Pw[4][16 * PADk];
    __shared__ int rowany[64];
    __shared__ int hasfix_s;

    const int tid  = threadIdx.x;
    const int lane = tid & 63;
    const int wave = tid >> 6;
    const int n = lane & 15;
    const int g = lane >> 4;

    const int qt = blockIdx.x & 15;
    const int bh = blockIdx.x >> 4;
    const int h  = bh & (NHc - 1);
    const int b  = bh >> 4;
    const int l0 = qt * 64;
    const bool causal = (is_causal_p[0] != 0);

    if (tid < 64) rowany[tid] = 0;
    if (tid == 0) hasfix_s = 0;
    __syncthreads();
    {
        const int row = tid >> 2, part = tid & 3;
        const int l = l0 + row;
        const int limit = causal ? l : (Sc - 1);
        const int* mrow = mask + ((size_t)b * Lc + l) * Sc;
        int any = 0;
        for (int s = part * 256; s < part * 256 + 256; ++s) {
            if (s <= limit && mrow[s] != 0) { any = 1; break; }
        }
        if (any) atomicOr(&rowany[row], 1);
    }
    __syncthreads();
    if (tid < 64 && rowany[tid] == 0) atomicOr(&hasfix_s, 1);
    __syncthreads();
    const bool hasfix = (hasfix_s != 0);

    const int qrow_frag = l0 + wave * 16 + n;
    const bf16* qp = qh + ((size_t)bh * Lc + qrow_frag) * DHc;
    const short8 qf0 = *(const short8*)(qp + g * 8);
    const short8 qf1 = *(const short8*)(qp + 32 + g * 8);

    floatx4 oacc[4];
    #pragma unroll
    for (int t = 0; t < 4; ++t) oacc[t] = (floatx4){0.f, 0.f, 0.f, 0.f};
    float m_run[4], l_run[4];
    #pragma unroll
    for (int r = 0; r < 4; ++r) { m_run[r] = -3.0e38f; l_run[r] = 0.f; }

    int nchunk = Sc / 64;
    if (causal && !hasfix) nchunk = qt + 1;

    for (int c = 0; c < nchunk; ++c) {
        const int s0 = c * 64;
        __syncthreads();
        #pragma unroll
        for (int it = 0; it < 2; ++it) {
            const int e  = tid * 8 + it * 2048;
            const int r0 = e >> 6, c0 = e & 63;
            *(uint4*)(Ks + r0 * PADk + c0) =
                *(const uint4*)(kh + ((size_t)bh * Sc + s0 + r0) * DHc + c0);
            *(uint4*)(Vs + r0 * PADk + c0) =
                *(const uint4*)(vt + ((size_t)bh * DHc + r0) * Sc + s0 + c0);
        }
        __syncthreads();

        float bi[4][4]; int mk[4][4];
        #pragma unroll
        for (int r = 0; r < 4; ++r) {
            const int l = l0 + wave * 16 + g * 4 + r;
            const size_t mb = ((size_t)b  * Lc + l) * Sc + s0 + n;
            const size_t pb = ((size_t)bh * Lc + l) * Sc + s0 + n;
            #pragma unroll
            for (int t = 0; t < 4; ++t) {
                mk[r][t] = mask[mb + 16 * t];
                bi[r][t] = pos_bias[pb + 16 * t];
            }
        }

        floatx4 scv[4];
        #pragma unroll
        for (int t = 0; t < 4; ++t) scv[t] = (floatx4){0.f, 0.f, 0.f, 0.f};
        #pragma unroll
        for (int t = 0; t < 4; ++t) {
            short8 kb0 = *(const short8*)(Ks + (16 * t + n) * PADk + g * 8);
            short8 kb1 = *(const short8*)(Ks + (16 * t + n) * PADk + 32 + g * 8);
            scv[t] = mfma_bf16(qf0, kb0, scv[t]);
            scv[t] = mfma_bf16(qf1, kb1, scv[t]);
        }

        #pragma unroll
        for (int r = 0; r < 4; ++r) {
            const int row = wave * 16 + g * 4 + r;
            const int l = l0 + row;
            const int limit = causal ? l : (Sc - 1);
            const bool fix = (rowany[row] == 0);
            float vals[4];
            #pragma unroll
            for (int t = 0; t < 4; ++t) {
                const int s = s0 + 16 * t + n;
                const bool ok = fix || (s <= limit && mk[r][t] != 0);
                vals[t] = ok ? scv[t][r] * 0.125f + bi[r][t] : -3.0e38f;
            }
            float cm = fmaxf(fmaxf(vals[0], vals[1]), fmaxf(vals[2], vals[3]));
            cm = fmaxf(cm, __shfl_xor(cm, 1));
            cm = fmaxf(cm, __shfl_xor(cm, 2));
            cm = fmaxf(cm, __shfl_xor(cm, 4));
            cm = fmaxf(cm, __shfl_xor(cm, 8));
            const float mnew = fmaxf(m_run[r], cm);
            const float alpha = __expf(m_run[r] - mnew);
            float csum = 0.f;
            #pragma unroll
            for (int t = 0; t < 4; ++t) {
                const float p = (vals[t] < -1.0e37f) ? 0.f : __expf(vals[t] - mnew);
                csum += p;
                Pw[wave][row % 16 * PADk + 16 * t + n] = __float2bfloat16(p);
            }
            csum += __shfl_xor(csum, 1);
            csum += __shfl_xor(csum, 2);
            csum += __shfl_xor(csum, 4);
            csum += __shfl_xor(csum, 8);
            l_run[r] = l_run[r] * alpha + csum;
            m_run[r] = mnew;
            #pragma unroll
            for (int t = 0; t < 4; ++t) oacc[t][r] *= alpha;
        }
        __syncthreads();

        #pragma unroll
        for (int sc2 = 0; sc2 < 2; ++sc2) {
            short8 pa = *(const short8*)(Pw[wave] + n * PADk + sc2 * 32 + g * 8);
            #pragma unroll
            for (int t = 0; t < 4; ++t) {
                short8 vb = *(const short8*)(Vs + (16 * t + n) * PADk + sc2 * 32 + g * 8);
                oacc[t] = mfma_bf16(pa, vb, oacc[t]);
            }
        }
    }

    #pragma unroll
    for (int r = 0; r < 4; ++r) {
        const int l = l0 + wave * 16 + g * 4 + r;
        const float inv = 1.f / l_run[r];
        #pragma unroll
        for (int t = 0; t < 4; ++t) {
            const int d = 16 * t + n;
            o[((size_t)(b * Lc + l)) * DIMc + h * DHc + d] =
                __float2bfloat16(oacc[t][r] * inv);
        }
    }
}

// ---------------------------------------------------------------------------
extern "C" void kernel_launch(void* const* d_in, const int* in_sizes, int n_in,
                              void* d_out, int out_size, void* d_ws, size_t ws_size,
                              hipStream_t stream)
{
    (void)in_sizes; (void)n_in; (void)out_size; (void)ws_size;

    const float* q        = (const float*)d_in[0];
    const float* k        = (const float*)d_in[1];
    const float* v        = (const float*)d_in[2];
    const int*   mask     = (const int*)d_in[3];
    const float* pos_bias = (const float*)d_in[4];
    const float* Wq = (const float*)d_in[5];
    const float* bq = (const float*)d_in[6];
    const float* Wk = (const float*)d_in[7];
    const float* bk = (const float*)d_in[8];
    const float* Wv = (const float*)d_in[9];
    const float* bv = (const float*)d_in[10];
    const float* Wp = (const float*)d_in[11];
    const float* bp = (const float*)d_in[12];
    const int*   is_causal = (const int*)d_in[13];

    const size_t per = (size_t)Bc * NHc * Lc * DHc;   // 4M elems
    const size_t wsz = (size_t)DIMc * DIMc;           // 1M elems
    bf16* qh  = (bf16*)d_ws;
    bf16* kh  = qh + per;
    bf16* vt  = kh + per;
    bf16* oh  = vt + per;
    bf16* qb  = oh + per;
    bf16* kb  = qb + per;
    bf16* vb  = kb + per;
    bf16* wqt = vb + per;
    bf16* wkt = wqt + wsz;
    bf16* wvt = wkt + wsz;
    bf16* wpt = wvt + wsz;
    float* outp = (float*)d_out;

    dim3 bb(256);

    prep_kernel<<<7168, bb, 0, stream>>>(q, k, v, Wq, Wk, Wv, Wp,
                                         qb, kb, vb, wqt, wkt, wvt, wpt);

    dim3 gg(32, 8);   // 4096/128 x 1024/128
    gemm_bt_kernel<bf16><<<gg, bb, 0, stream>>>(qb, wqt, bq, qh, 1);
    gemm_bt_kernel<bf16><<<gg, bb, 0, stream>>>(kb, wkt, bk, kh, 1);
    gemm_bt_kernel<bf16><<<gg, bb, 0, stream>>>(vb, wvt, bv, vt, 2);

    flash_attn_kernel<<<(Bc * NHc) * (Lc / 64), bb, 0, stream>>>(
        qh, kh, vt, mask, pos_bias, is_causal, oh);

    gemm_bt_kernel<float><<<gg, bb, 0, stream>>>(oh, wpt, bp, outp, 0);
}